// Round 1
// baseline (903.785 us; speedup 1.0000x reference)
//
#include <hip/hip_runtime.h>
#include <hip/hip_bf16.h>

// Problem constants (from reference)
constexpr int BB   = 4;
constexpr int CIN  = 64;
constexpr int COUT = 64;
constexpr int HH   = 384;
constexpr int WW   = 384;
constexpr int HWc  = HH * WW;          // 147456
constexpr int NPIX = BB * HWc;         // 589824
constexpr int CMID = 16;               // COUT / R
constexpr int KPOS = CIN * 9;          // 576 taps per output channel

// ---------------- route flags ----------------
__global__ void k_flags(const int* __restrict__ mi, const int* __restrict__ ii,
                        unsigned char* __restrict__ flags, int half) {
    int i = blockIdx.x * blockDim.x + threadIdx.x;
    if (i < half) {
        flags[mi[i]] = 1;
        flags[ii[i]] = 0;
    }
}

// ------------- weight transpose: w[c][pos] -> wt[pos][c] (contiguous in c) -------------
__global__ void k_transpose(const float* __restrict__ hw_, const float* __restrict__ l1w,
                            float* __restrict__ wt_h, float* __restrict__ wt_l1) {
    int i = blockIdx.x * blockDim.x + threadIdx.x;
    if (i < KPOS * COUT) {
        int pos = i >> 6, c = i & 63;
        wt_h[i] = hw_[c * KPOS + pos];
    }
    if (i < KPOS * CMID) {
        int pos = i >> 4, c = i & 15;
        wt_l1[i] = l1w[c * KPOS + pos];
    }
}

// ------------- fused dense-both + routed select -------------
// One thread per pixel. 64 high accumulators + 16 mid accumulators.
// Weight reads are wave-uniform (loop-var indices into transposed tables) ->
// compiler emits vectorized scalar loads (s_load_dwordx16), SGPR-operand FMAs.
__global__ __launch_bounds__(256) void k_conv_routed(
    const float* __restrict__ x,
    const float* __restrict__ wt_h,    // [KPOS][COUT]
    const float* __restrict__ wt_l1,   // [KPOS][CMID]
    const float* __restrict__ l2w,     // [COUT][CMID]
    const unsigned char* __restrict__ flags,
    float* __restrict__ out)
{
    const int n  = blockIdx.x * 256 + threadIdx.x;   // grid sized exactly NPIX/256
    const int b  = n / HWc;
    const int hw = n - b * HWc;
    const int yy = hw / WW;
    const int xx = hw - yy * WW;

    float hacc[COUT];
    float macc[CMID];
#pragma unroll
    for (int c = 0; c < COUT; ++c) hacc[c] = 0.f;
#pragma unroll
    for (int c = 0; c < CMID; ++c) macc[c] = 0.f;

    const float* xb = x + (size_t)b * CIN * HWc;

    for (int cin = 0; cin < CIN; ++cin) {
        const float* xc = xb + cin * HWc;
#pragma unroll
        for (int ky = 0; ky < 3; ++ky) {
            const int y   = yy + ky - 1;
            const bool yok = (unsigned)y < (unsigned)HH;
            const float* xr = xc + (yok ? y : yy) * WW;
#pragma unroll
            for (int kx = 0; kx < 3; ++kx) {
                const int xq  = xx + kx - 1;
                const bool ok = yok && ((unsigned)xq < (unsigned)WW);
                float xv = xr[ok ? xq : xx];     // clamped-safe address
                if (!ok) xv = 0.f;
                const int pos = cin * 9 + ky * 3 + kx;
                const float* wh = wt_h  + pos * COUT;
                const float* wl = wt_l1 + pos * CMID;
#pragma unroll
                for (int c = 0; c < COUT; ++c)
                    hacc[c] = fmaf(xv, wh[c], hacc[c]);
#pragma unroll
                for (int c = 0; c < CMID; ++c)
                    macc[c] = fmaf(xv, wl[c], macc[c]);
            }
        }
    }

    const bool is_high = flags[n] != 0;
    float* ob = out + (size_t)b * COUT * HWc + hw;
#pragma unroll
    for (int c = 0; c < COUT; ++c) {
        float lo = 0.f;
#pragma unroll
        for (int j = 0; j < CMID; ++j)
            lo = fmaf(macc[j], l2w[c * CMID + j], lo);
        ob[(size_t)c * HWc] = is_high ? hacc[c] : lo;
    }
}

extern "C" void kernel_launch(void* const* d_in, const int* in_sizes, int n_in,
                              void* d_out, int out_size, void* d_ws, size_t ws_size,
                              hipStream_t stream) {
    const float* x    = (const float*)d_in[0];
    const float* hw_  = (const float*)d_in[1];
    const float* l1w  = (const float*)d_in[2];
    const float* l2w  = (const float*)d_in[3];
    const int*   mi   = (const int*)d_in[4];
    const int*   ii   = (const int*)d_in[5];
    float*       out  = (float*)d_out;

    // workspace carve (flags is 589824 B, 256-aligned already)
    unsigned char* flags = (unsigned char*)d_ws;
    float* wt_h  = (float*)((char*)d_ws + NPIX);                       // 576*64 floats
    float* wt_l1 = (float*)((char*)d_ws + NPIX + KPOS * COUT * 4);     // 576*16 floats

    const int half = NPIX / 2;
    k_flags<<<(half + 255) / 256, 256, 0, stream>>>(mi, ii, flags, half);
    k_transpose<<<(KPOS * COUT + 255) / 256, 256, 0, stream>>>(hw_, l1w, wt_h, wt_l1);
    k_conv_routed<<<NPIX / 256, 256, 0, stream>>>(x, wt_h, wt_l1, l2w, flags, out);
}

// Round 2
// 345.335 us; speedup vs baseline: 2.6171x; 2.6171x over previous
//
#include <hip/hip_runtime.h>
#include <hip/hip_bf16.h>
#include <stdint.h>

typedef __attribute__((ext_vector_type(8))) short  short8;
typedef __attribute__((ext_vector_type(4))) float  float4_t;
typedef __attribute__((ext_vector_type(4))) int    int4_t;

constexpr int BB = 4, CIN = 64, COUT = 64, HH = 384, WW = 384;
constexpr int HWc  = HH * WW;        // 147456
constexpr int NPIX = BB * HWc;       // 589824
constexpr int WP   = 386;            // padded H/W for x_t
// main-kernel tiling
constexpr int TR = 12, TC = 32;      // pixel tile per WG
constexpr int SR = TR + 2, SC = TC + 2;  // staged rows/cols (14, 34)

__device__ __forceinline__ unsigned short f2bf(float f) {
    unsigned u = __builtin_bit_cast(unsigned, f);
    unsigned r = u + 0x7FFFu + ((u >> 16) & 1u);   // RNE
    return (unsigned short)(r >> 16);
}

// ---------------- route flags ----------------
__global__ void k_flags(const int* __restrict__ mi, const int* __restrict__ ii,
                        unsigned char* __restrict__ flags, int half) {
    int i = blockIdx.x * blockDim.x + threadIdx.x;
    if (i < half) { flags[mi[i]] = 1; flags[ii[i]] = 0; }
}

// ---------------- zero x_t borders (ws is poisoned every call) ----------------
__global__ void k_zb(unsigned short* __restrict__ xt) {
    int i = blockIdx.x * 256 + threadIdx.x;
    if (i >= 4 * 98560) return;                 // per b: 2*386*64 + 2*384*64
    int b = i / 98560, j = i % 98560;
    size_t off;
    if (j < 2 * 386 * 64) {
        int yt  = (j >= 386 * 64) ? 385 : 0;
        int jj  = j % (386 * 64);
        int col = jj >> 6, cin = jj & 63;
        off = (((size_t)b * WP + yt) * WP + col) * 64 + cin;
    } else {
        int j2  = j - 2 * 386 * 64;
        int xtc = (j2 >= 384 * 64) ? 385 : 0;
        int jj  = j2 % (384 * 64);
        int row = 1 + (jj >> 6), cin = jj & 63;
        off = (((size_t)b * WP + row) * WP + xtc) * 64 + cin;
    }
    xt[off] = 0;
}

// ---------------- x NCHW fp32 -> x_t [b][y+1][x+1][cin] bf16 ----------------
__global__ __launch_bounds__(256) void k_xpose(const float* __restrict__ x,
                                               unsigned short* __restrict__ xt) {
    __shared__ float tile[64][65];
    const int xt0 = blockIdx.x * 64;   // 0..5
    const int y   = blockIdx.y;        // 0..383
    const int b   = blockIdx.z;
    const int t   = threadIdx.x;
    {   // coalesced read along x
        int col = t & 63, ci0 = t >> 6;
        const float* xp = x + (size_t)(b * 64) * HWc + y * WW + xt0 + col;
#pragma unroll
        for (int i = 0; i < 16; i++) {
            int cin = i * 4 + ci0;
            tile[cin][col] = xp[(size_t)cin * HWc];
        }
    }
    __syncthreads();
    {   // coalesced write along cin (bf16 pairs)
        int c2 = (t & 31) * 2, colw = t >> 5;
        unsigned short* op = xt + (((size_t)b * WP + (y + 1)) * WP + (xt0 + 1)) * 64;
#pragma unroll
        for (int i = 0; i < 8; i++) {
            int cc = colw + i * 8;
            unsigned lo = f2bf(tile[c2][cc]);
            unsigned hi = f2bf(tile[c2 + 1][cc]);
            *(unsigned*)(op + (size_t)cc * 64 + c2) = lo | (hi << 16);
        }
    }
}

// ---------------- weight pack: fragment-ready layouts ----------------
// Wp[chunk 0..17][tile 0..4][lane 0..63][8] bf16 ; chunk = tap*2 + h, k = 32h + quad*8 + j
// Ap2[tile 0..3][lane][8] bf16 for the 1x1 (k = (c>>2)*8 + (c&3), j>=4 zero)
__global__ void k_wpack(const float* __restrict__ hw_, const float* __restrict__ l1w,
                        const float* __restrict__ l2w,
                        unsigned short* __restrict__ Wp, unsigned short* __restrict__ Ap2) {
    int i = blockIdx.x * 256 + threadIdx.x;
    if (i < 18 * 5 * 64) {
        int lane = i & 63, tile = (i >> 6) % 5, chunk = i / 320;
        int tap = chunk >> 1, h = chunk & 1, ky = tap / 3, kx = tap % 3;
        int m = lane & 15, quad = lane >> 4;
        for (int j = 0; j < 8; j++) {
            int cin = h * 32 + quad * 8 + j;
            float wv;
            if (tile < 4) { int co = tile * 16 + m; wv = hw_[((co * 64 + cin) * 3 + ky) * 3 + kx]; }
            else          { wv = l1w[((m * 64 + cin) * 3 + ky) * 3 + kx]; }
            Wp[(size_t)i * 8 + j] = f2bf(wv);
        }
    }
    if (i < 4 * 64) {
        int lane = i & 63, tile = i >> 6;
        int m = lane & 15, quad = lane >> 4;
        for (int j = 0; j < 8; j++) {
            unsigned short v = 0;
            if (j < 4) { int c = quad * 4 + j; v = f2bf(l2w[(tile * 16 + m) * 16 + c]); }
            Ap2[(size_t)i * 8 + j] = v;
        }
    }
}

// ---------------- main fused MFMA kernel ----------------
// WG = 256 thr = 4 waves; pixel tile TR x TC; wave w owns rows 3w..3w+2 (6 frags of 16 px).
// M-dim = channels (4 high tiles + 1 mid tile), N-dim = pixels.
__global__ __launch_bounds__(256, 2) void k_main(
    const unsigned short* __restrict__ xt,
    const unsigned short* __restrict__ Wp,
    const unsigned short* __restrict__ Ap2,
    const unsigned char* __restrict__ flags,
    float* __restrict__ out)
{
    __shared__ __align__(16) unsigned short X[SR * SC * 64];  // 60928 B, cin-swizzled

    const int tid = threadIdx.x;
    const int x0  = blockIdx.x * TC;
    const int y0  = blockIdx.y * TR;
    const int b   = blockIdx.z;

    // ---- stage tile (rows y0-1..y0+12, cols x0-1..x0+32 in unpadded coords) ----
    const unsigned short* xbase = xt + (((size_t)b * WP + y0) * WP + x0) * 64;
    for (int s = tid; s < SR * SC * 8; s += 256) {
        int c8 = s & 7;
        int xh = (s >> 3) % SC;
        int rh = s / (SC * 8);
        int4_t v = *(const int4_t*)(xbase + ((size_t)rh * WP + xh) * 64 + c8 * 8);
        int blk = c8 ^ (xh & 7);                              // bank-conflict swizzle
        *(int4_t*)&X[(rh * SC + xh) * 64 + blk * 8] = v;
    }
    __syncthreads();

    const int lane = tid & 63;
    const int w    = tid >> 6;
    const int n16  = lane & 15;
    const int quad = lane >> 4;

    float4_t acc[5][6];
#pragma unroll
    for (int t = 0; t < 5; t++)
#pragma unroll
        for (int f = 0; f < 6; f++) acc[t][f] = (float4_t)0.0f;

    const int4_t* wp4 = (const int4_t*)Wp;
    short8 a_cur[5], a_nxt[5];
#pragma unroll
    for (int t = 0; t < 5; t++)
        a_cur[t] = __builtin_bit_cast(short8, wp4[t * 64 + lane]);

#pragma unroll 1
    for (int chunk = 0; chunk < 18; chunk++) {
        if (chunk < 17) {
#pragma unroll
            for (int t = 0; t < 5; t++)
                a_nxt[t] = __builtin_bit_cast(short8, wp4[((chunk + 1) * 5 + t) * 64 + lane]);
        }
        const int tap = chunk >> 1, h = chunk & 1;
        const int ky = tap / 3, kx = tap % 3;
        short8 bf[6];
#pragma unroll
        for (int f = 0; f < 6; f++) {
            int idx = w * 6 + f;
            int r = idx >> 1, ch = idx & 1;
            int xh  = ch * 16 + n16 + kx;
            int blk = (h * 4 + quad) ^ (xh & 7);
            bf[f] = __builtin_bit_cast(short8,
                    *(const int4_t*)&X[((r + ky) * SC + xh) * 64 + blk * 8]);
        }
#pragma unroll
        for (int f = 0; f < 6; f++)
#pragma unroll
            for (int t = 0; t < 5; t++)
                acc[t][f] = __builtin_amdgcn_mfma_f32_16x16x32_bf16(a_cur[t], bf[f], acc[t][f], 0, 0, 0);
#pragma unroll
        for (int t = 0; t < 5; t++) a_cur[t] = a_nxt[t];
    }

    // ---- epilogue: 1x1 low path via MFMA, routed select, store ----
    short8 a2[4];
    const int4_t* ap4 = (const int4_t*)Ap2;
#pragma unroll
    for (int t = 0; t < 4; t++)
        a2[t] = __builtin_bit_cast(short8, ap4[t * 64 + lane]);

#pragma unroll
    for (int f = 0; f < 6; f++) {
        int idx = w * 6 + f;
        int r = idx >> 1, ch = idx & 1;
        float4_t m4 = acc[4][f];
        short8 bfrag;
#pragma unroll
        for (int j = 0; j < 8; j++)
            bfrag[j] = (j < 4) ? (short)f2bf(m4[j]) : (short)0;

        int gy = y0 + r, gx = x0 + ch * 16 + n16;
        bool hiF = flags[b * HWc + gy * WW + gx] != 0;
        float* ob = out + (size_t)b * COUT * HWc + gy * WW + gx;
#pragma unroll
        for (int t = 0; t < 4; t++) {
            float4_t low = __builtin_amdgcn_mfma_f32_16x16x32_bf16(a2[t], bfrag, (float4_t)0.0f, 0, 0, 0);
            float4_t hi = acc[t][f];
#pragma unroll
            for (int i = 0; i < 4; i++) {
                int co = t * 16 + quad * 4 + i;
                ob[(size_t)co * HWc] = hiF ? hi[i] : low[i];
            }
        }
    }
}

extern "C" void kernel_launch(void* const* d_in, const int* in_sizes, int n_in,
                              void* d_out, int out_size, void* d_ws, size_t ws_size,
                              hipStream_t stream) {
    const float* x   = (const float*)d_in[0];
    const float* hw_ = (const float*)d_in[1];
    const float* l1w = (const float*)d_in[2];
    const float* l2w = (const float*)d_in[3];
    const int*   mi  = (const int*)d_in[4];
    const int*   ii  = (const int*)d_in[5];
    float*       out = (float*)d_out;

    // ws carve
    unsigned short* xt    = (unsigned short*)d_ws;                         // 76,244,992 B
    size_t off = (size_t)4 * WP * WP * 64 * 2;
    unsigned char*  flags = (unsigned char*)d_ws + off;  off += NPIX;      // 589,824 B
    off = (off + 15) & ~(size_t)15;
    unsigned short* Wp    = (unsigned short*)((char*)d_ws + off); off += 18 * 5 * 64 * 8 * 2;
    unsigned short* Ap2   = (unsigned short*)((char*)d_ws + off);

    const int half = NPIX / 2;
    k_flags<<<(half + 255) / 256, 256, 0, stream>>>(mi, ii, flags, half);
    k_zb<<<(4 * 98560 + 255) / 256, 256, 0, stream>>>(xt);
    k_xpose<<<dim3(WW / 64, HH, BB), 256, 0, stream>>>(x, xt);
    k_wpack<<<(18 * 5 * 64 + 255) / 256, 256, 0, stream>>>(hw_, l1w, l2w, Wp, Ap2);
    k_main<<<dim3(WW / TC, HH / TR, BB), 256, 0, stream>>>(xt, Wp, Ap2, flags, out);
}

// Round 3
// 344.701 us; speedup vs baseline: 2.6219x; 1.0018x over previous
//
#include <hip/hip_runtime.h>
#include <hip/hip_bf16.h>
#include <stdint.h>

typedef __attribute__((ext_vector_type(8))) short  short8;
typedef __attribute__((ext_vector_type(4))) float  float4_t;
typedef __attribute__((ext_vector_type(4))) int    int4_t;

constexpr int BB = 4, CIN = 64, COUT = 64, HH = 384, WW = 384;
constexpr int HWc  = HH * WW;        // 147456
constexpr int NPIX = BB * HWc;       // 589824
// main-kernel tiling
constexpr int TR = 12, TC = 32;          // pixel tile per WG
constexpr int SR = TR + 2, SC = TC + 2;  // staged rows/cols (14, 34)
constexpr int NGRP = SR * SC * 8;        // 3808 8-cin groups staged per block

__device__ __forceinline__ unsigned short f2bf(float f) {
    unsigned u = __builtin_bit_cast(unsigned, f);
    unsigned r = u + 0x7FFFu + ((u >> 16) & 1u);   // RNE
    return (unsigned short)(r >> 16);
}

// ---------------- route flags ----------------
__global__ void k_flags(const int* __restrict__ mi, const int* __restrict__ ii,
                        unsigned char* __restrict__ flags, int half) {
    int i = blockIdx.x * blockDim.x + threadIdx.x;
    if (i < half) { flags[mi[i]] = 1; flags[ii[i]] = 0; }
}

// ---------------- weight pack: fragment-ready layouts ----------------
// Wp[chunk 0..17][tile 0..4][lane 0..63][8] bf16 ; chunk = tap*2 + h, k = 32h + quad*8 + j
// Ap2[tile 0..3][lane][8] bf16 for the 1x1 (k = (c>>2)*8 + (c&3), j>=4 zero)
__global__ void k_wpack(const float* __restrict__ hw_, const float* __restrict__ l1w,
                        const float* __restrict__ l2w,
                        unsigned short* __restrict__ Wp, unsigned short* __restrict__ Ap2) {
    int i = blockIdx.x * 256 + threadIdx.x;
    if (i < 18 * 5 * 64) {
        int lane = i & 63, tile = (i >> 6) % 5, chunk = i / 320;
        int tap = chunk >> 1, h = chunk & 1, ky = tap / 3, kx = tap % 3;
        int m = lane & 15, quad = lane >> 4;
        for (int j = 0; j < 8; j++) {
            int cin = h * 32 + quad * 8 + j;
            float wv;
            if (tile < 4) { int co = tile * 16 + m; wv = hw_[((co * 64 + cin) * 3 + ky) * 3 + kx]; }
            else          { wv = l1w[((m * 64 + cin) * 3 + ky) * 3 + kx]; }
            Wp[(size_t)i * 8 + j] = f2bf(wv);
        }
    }
    if (i < 4 * 64) {
        int lane = i & 63, tile = i >> 6;
        int m = lane & 15, quad = lane >> 4;
        for (int j = 0; j < 8; j++) {
            unsigned short v = 0;
            if (j < 4) { int c = quad * 4 + j; v = f2bf(l2w[(tile * 16 + m) * 16 + c]); }
            Ap2[(size_t)i * 8 + j] = v;
        }
    }
}

// ---------------- main fused MFMA kernel (reads NCHW fp32 directly) ----------------
// WG = 256 thr = 4 waves; pixel tile TR x TC; wave w owns rows 3w..3w+2 (6 frags of 16 px).
// M-dim = channels (4 high tiles + 1 mid tile), N-dim = pixels.
// Staging: thread owns (pixel, 8-cin group) -> 8 coalesced dword loads at stride HWc,
// pack bf16x8, one ds_write_b128 into the swizzled fragment layout. Borders -> 0.
__global__ __launch_bounds__(256, 2) void k_main(
    const float* __restrict__ x,
    const unsigned short* __restrict__ Wp,
    const unsigned short* __restrict__ Ap2,
    const unsigned char* __restrict__ flags,
    float* __restrict__ out)
{
    __shared__ __align__(16) unsigned short X[SR * SC * 64];  // 60928 B, swizzled

    const int tid = threadIdx.x;
    const int x0  = blockIdx.x * TC;
    const int y0  = blockIdx.y * TR;
    const int b   = blockIdx.z;

    // ---- stage tile: global NCHW fp32 -> LDS bf16 fragment layout ----
    const float* xb = x + (size_t)b * CIN * HWc;
#pragma unroll 1
    for (int s = tid; s < NGRP; s += 256) {
        int q   = s / (SR * SC);          // 8-cin group 0..7
        int p   = s - q * (SR * SC);      // pixel 0..475 (row*SC+col)
        int row = p / SC;
        int col = p - row * SC;
        int gy  = y0 + row - 1;
        int gx  = x0 + col - 1;
        bool ok = ((unsigned)gy < (unsigned)HH) && ((unsigned)gx < (unsigned)WW);
        int off = ok ? (gy * WW + gx) : 0;     // clamped-safe address
        const float* xp = xb + (size_t)(q * 8) * HWc + off;
        unsigned pk[4];
#pragma unroll
        for (int jj = 0; jj < 4; jj++) {
            float f0 = xp[(size_t)(2 * jj)     * HWc];
            float f1 = xp[(size_t)(2 * jj + 1) * HWc];
            if (!ok) { f0 = 0.f; f1 = 0.f; }
            pk[jj] = (unsigned)f2bf(f0) | ((unsigned)f2bf(f1) << 16);
        }
        int blk = q ^ (col & 7);               // bank-conflict swizzle (matches reader)
        *(int4_t*)&X[p * 64 + blk * 8] = *(int4_t*)pk;
    }
    __syncthreads();

    const int lane = tid & 63;
    const int w    = tid >> 6;
    const int n16  = lane & 15;
    const int quad = lane >> 4;

    float4_t acc[5][6];
#pragma unroll
    for (int t = 0; t < 5; t++)
#pragma unroll
        for (int f = 0; f < 6; f++) acc[t][f] = (float4_t)0.0f;

    const int4_t* wp4 = (const int4_t*)Wp;
    short8 a_cur[5], a_nxt[5];
#pragma unroll
    for (int t = 0; t < 5; t++)
        a_cur[t] = __builtin_bit_cast(short8, wp4[t * 64 + lane]);

#pragma unroll 1
    for (int chunk = 0; chunk < 18; chunk++) {
        if (chunk < 17) {
#pragma unroll
            for (int t = 0; t < 5; t++)
                a_nxt[t] = __builtin_bit_cast(short8, wp4[((chunk + 1) * 5 + t) * 64 + lane]);
        }
        const int tap = chunk >> 1, h = chunk & 1;
        const int ky = tap / 3, kx = tap % 3;
        short8 bf[6];
#pragma unroll
        for (int f = 0; f < 6; f++) {
            int idx = w * 6 + f;
            int r = idx >> 1, ch = idx & 1;
            int xh  = ch * 16 + n16 + kx;
            int blk = (h * 4 + quad) ^ (xh & 7);
            bf[f] = __builtin_bit_cast(short8,
                    *(const int4_t*)&X[((r + ky) * SC + xh) * 64 + blk * 8]);
        }
#pragma unroll
        for (int f = 0; f < 6; f++)
#pragma unroll
            for (int t = 0; t < 5; t++)
                acc[t][f] = __builtin_amdgcn_mfma_f32_16x16x32_bf16(a_cur[t], bf[f], acc[t][f], 0, 0, 0);
#pragma unroll
        for (int t = 0; t < 5; t++) a_cur[t] = a_nxt[t];
    }

    // ---- epilogue: 1x1 low path via MFMA, routed select, store ----
    short8 a2[4];
    const int4_t* ap4 = (const int4_t*)Ap2;
#pragma unroll
    for (int t = 0; t < 4; t++)
        a2[t] = __builtin_bit_cast(short8, ap4[t * 64 + lane]);

#pragma unroll
    for (int f = 0; f < 6; f++) {
        int idx = w * 6 + f;
        int r = idx >> 1, ch = idx & 1;
        float4_t m4 = acc[4][f];
        short8 bfrag;
#pragma unroll
        for (int j = 0; j < 8; j++)
            bfrag[j] = (j < 4) ? (short)f2bf(m4[j]) : (short)0;

        int gy = y0 + r, gx = x0 + ch * 16 + n16;
        bool hiF = flags[b * HWc + gy * WW + gx] != 0;
        float* ob = out + (size_t)b * COUT * HWc + gy * WW + gx;
#pragma unroll
        for (int t = 0; t < 4; t++) {
            float4_t low = __builtin_amdgcn_mfma_f32_16x16x32_bf16(a2[t], bfrag, (float4_t)0.0f, 0, 0, 0);
            float4_t hi = acc[t][f];
#pragma unroll
            for (int i = 0; i < 4; i++) {
                int co = t * 16 + quad * 4 + i;
                ob[(size_t)co * HWc] = hiF ? hi[i] : low[i];
            }
        }
    }
}

extern "C" void kernel_launch(void* const* d_in, const int* in_sizes, int n_in,
                              void* d_out, int out_size, void* d_ws, size_t ws_size,
                              hipStream_t stream) {
    const float* x   = (const float*)d_in[0];
    const float* hw_ = (const float*)d_in[1];
    const float* l1w = (const float*)d_in[2];
    const float* l2w = (const float*)d_in[3];
    const int*   mi  = (const int*)d_in[4];
    const int*   ii  = (const int*)d_in[5];
    float*       out = (float*)d_out;

    // ws carve
    unsigned char*  flags = (unsigned char*)d_ws;
    size_t off = (NPIX + 15) & ~(size_t)15;
    unsigned short* Wp    = (unsigned short*)((char*)d_ws + off); off += 18 * 5 * 64 * 8 * 2;
    unsigned short* Ap2   = (unsigned short*)((char*)d_ws + off);

    const int half = NPIX / 2;
    k_flags<<<(half + 255) / 256, 256, 0, stream>>>(mi, ii, flags, half);
    k_wpack<<<(18 * 5 * 64 + 255) / 256, 256, 0, stream>>>(hw_, l1w, l2w, Wp, Ap2);
    k_main<<<dim3(WW / TC, HH / TR, BB), 256, 0, stream>>>(x, Wp, Ap2, flags, out);
}

// Round 4
// 328.701 us; speedup vs baseline: 2.7496x; 1.0487x over previous
//
#include <hip/hip_runtime.h>
#include <hip/hip_bf16.h>
#include <stdint.h>

typedef __attribute__((ext_vector_type(8))) short  short8;
typedef __attribute__((ext_vector_type(4))) float  float4_t;
typedef __attribute__((ext_vector_type(4))) int    int4_t;

constexpr int BB = 4, CIN = 64, COUT = 64, HH = 384, WW = 384;
constexpr int HWc  = HH * WW;        // 147456
constexpr int NPIX = BB * HWc;       // 589824
// main-kernel tiling
constexpr int TR = 8, TC = 32;           // pixel tile per WG
constexpr int SR = TR + 2, SC = TC + 2;  // staged rows/cols (10, 34)
constexpr int NTASK = SR * 9 * 8;        // staging tasks: row x 4-px-group x 8-cin-group = 720

__device__ __forceinline__ unsigned short f2bf(float f) {
    unsigned u = __builtin_bit_cast(unsigned, f);
    unsigned r = u + 0x7FFFu + ((u >> 16) & 1u);   // RNE
    return (unsigned short)(r >> 16);
}

// ---------------- route flags ----------------
__global__ void k_flags(const int* __restrict__ mi, const int* __restrict__ ii,
                        unsigned char* __restrict__ flags, int half) {
    int i = blockIdx.x * blockDim.x + threadIdx.x;
    if (i < half) { flags[mi[i]] = 1; flags[ii[i]] = 0; }
}

// ---------------- weight pack: fragment-ready layouts ----------------
// Wp[chunk 0..17][tile 0..4][lane 0..63][8] bf16 ; chunk = tap*2 + h, k = 32h + quad*8 + j
// Ap2[tile 0..3][lane][8] bf16 for the 1x1 (k = (c>>2)*8 + (c&3), j>=4 zero)
__global__ void k_wpack(const float* __restrict__ hw_, const float* __restrict__ l1w,
                        const float* __restrict__ l2w,
                        unsigned short* __restrict__ Wp, unsigned short* __restrict__ Ap2) {
    int i = blockIdx.x * 256 + threadIdx.x;
    if (i < 18 * 5 * 64) {
        int lane = i & 63, tile = (i >> 6) % 5, chunk = i / 320;
        int tap = chunk >> 1, h = chunk & 1, ky = tap / 3, kx = tap % 3;
        int m = lane & 15, quad = lane >> 4;
        for (int j = 0; j < 8; j++) {
            int cin = h * 32 + quad * 8 + j;
            float wv;
            if (tile < 4) { int co = tile * 16 + m; wv = hw_[((co * 64 + cin) * 3 + ky) * 3 + kx]; }
            else          { wv = l1w[((m * 64 + cin) * 3 + ky) * 3 + kx]; }
            Wp[(size_t)i * 8 + j] = f2bf(wv);
        }
    }
    if (i < 4 * 64) {
        int lane = i & 63, tile = i >> 6;
        int m = lane & 15, quad = lane >> 4;
        for (int j = 0; j < 8; j++) {
            unsigned short v = 0;
            if (j < 4) { int c = quad * 4 + j; v = f2bf(l2w[(tile * 16 + m) * 16 + c]); }
            Ap2[(size_t)i * 8 + j] = v;
        }
    }
}

// ---------------- main fused MFMA kernel (reads NCHW fp32 directly) ----------------
// WG = 256 thr = 4 waves; pixel tile TR(8) x TC(32); wave w owns rows 2w,2w+1 (4 frags).
// Staging task = (row, 4-px group, 8-cin group): 8x global_load_dwordx4 (4 px x 8 cin),
// register transpose + f2bf, 4x ds_write_b128 into swizzled fragment layout.
__global__ __launch_bounds__(256, 3) void k_main(
    const float* __restrict__ x,
    const unsigned short* __restrict__ Wp,
    const unsigned short* __restrict__ Ap2,
    const unsigned char* __restrict__ flags,
    float* __restrict__ out)
{
    __shared__ __align__(16) unsigned short X[SR * SC * 64];  // 43520 B -> 3 blocks/CU

    const int tid = threadIdx.x;
    const int x0  = blockIdx.x * TC;
    const int y0  = blockIdx.y * TR;
    const int b   = blockIdx.z;

    // ---- stage tile: global NCHW fp32 -> LDS bf16 fragment layout ----
    const float* xb = x + (size_t)b * CIN * HWc;
#pragma unroll 1
    for (int t = tid; t < NTASK; t += 256) {
        int g   = t % 9;                 // 4-px group (cols 4g-1 .. 4g+2 of tile)
        int q   = (t / 9) & 7;           // 8-cin group
        int row = t / 72;
        int gy  = y0 + row - 1;
        int gx0 = x0 - 1 + g * 4;
        bool yok  = (unsigned)gy < (unsigned)HH;
        bool fast = yok && (gx0 >= 0) && (gx0 <= WW - 4);
        const float* xp = xb + (size_t)(q * 8) * HWc + gy * WW + gx0;
        float4_t v[8];
        if (fast) {
#pragma unroll
            for (int c = 0; c < 8; c++)
                v[c] = *(const float4_t*)(xp + (size_t)c * HWc);
        } else {
#pragma unroll
            for (int c = 0; c < 8; c++)
#pragma unroll
                for (int e = 0; e < 4; e++) {
                    bool ok = yok && ((unsigned)(gx0 + e) < (unsigned)WW);
                    v[c][e] = ok ? xp[(size_t)c * HWc + e] : 0.f;
                }
        }
#pragma unroll
        for (int e = 0; e < 4; e++) {
            int col = g * 4 + e;
            if (col < SC) {
                unsigned pk[4];
#pragma unroll
                for (int jj = 0; jj < 4; jj++)
                    pk[jj] = (unsigned)f2bf(v[2 * jj][e]) | ((unsigned)f2bf(v[2 * jj + 1][e]) << 16);
                int blk = q ^ (col & 7);
                *(int4_t*)&X[(row * SC + col) * 64 + blk * 8] = *(int4_t*)pk;
            }
        }
    }
    __syncthreads();

    const int lane = tid & 63;
    const int w    = tid >> 6;
    const int n16  = lane & 15;
    const int quad = lane >> 4;

    float4_t acc[5][4];
#pragma unroll
    for (int t = 0; t < 5; t++)
#pragma unroll
        for (int f = 0; f < 4; f++) acc[t][f] = (float4_t)0.0f;

    const int4_t* wp4 = (const int4_t*)Wp;
    short8 a_cur[5], a_nxt[5];
#pragma unroll
    for (int t = 0; t < 5; t++)
        a_cur[t] = __builtin_bit_cast(short8, wp4[t * 64 + lane]);

#pragma unroll 1
    for (int chunk = 0; chunk < 18; chunk++) {
        if (chunk < 17) {
#pragma unroll
            for (int t = 0; t < 5; t++)
                a_nxt[t] = __builtin_bit_cast(short8, wp4[((chunk + 1) * 5 + t) * 64 + lane]);
        }
        const int tap = chunk >> 1, h = chunk & 1;
        const int ky = tap / 3, kx = tap % 3;
        short8 bf[4];
#pragma unroll
        for (int f = 0; f < 4; f++) {
            int r  = 2 * w + (f >> 1);
            int ch = f & 1;
            int xh  = ch * 16 + n16 + kx;
            int blk = (h * 4 + quad) ^ (xh & 7);
            bf[f] = __builtin_bit_cast(short8,
                    *(const int4_t*)&X[((r + ky) * SC + xh) * 64 + blk * 8]);
        }
#pragma unroll
        for (int f = 0; f < 4; f++)
#pragma unroll
            for (int t = 0; t < 5; t++)
                acc[t][f] = __builtin_amdgcn_mfma_f32_16x16x32_bf16(a_cur[t], bf[f], acc[t][f], 0, 0, 0);
#pragma unroll
        for (int t = 0; t < 5; t++) a_cur[t] = a_nxt[t];
    }

    // ---- epilogue: 1x1 low path via MFMA, routed select, store ----
    short8 a2[4];
    const int4_t* ap4 = (const int4_t*)Ap2;
#pragma unroll
    for (int t = 0; t < 4; t++)
        a2[t] = __builtin_bit_cast(short8, ap4[t * 64 + lane]);

#pragma unroll
    for (int f = 0; f < 4; f++) {
        int r  = 2 * w + (f >> 1);
        int ch = f & 1;
        float4_t m4 = acc[4][f];
        short8 bfrag;
#pragma unroll
        for (int j = 0; j < 8; j++)
            bfrag[j] = (j < 4) ? (short)f2bf(m4[j]) : (short)0;

        int gy = y0 + r, gx = x0 + ch * 16 + n16;
        bool hiF = flags[b * HWc + gy * WW + gx] != 0;
        float* ob = out + (size_t)b * COUT * HWc + gy * WW + gx;
#pragma unroll
        for (int t = 0; t < 4; t++) {
            float4_t low = __builtin_amdgcn_mfma_f32_16x16x32_bf16(a2[t], bfrag, (float4_t)0.0f, 0, 0, 0);
            float4_t hi = acc[t][f];
#pragma unroll
            for (int i = 0; i < 4; i++) {
                int co = t * 16 + quad * 4 + i;
                ob[(size_t)co * HWc] = hiF ? hi[i] : low[i];
            }
        }
    }
}

extern "C" void kernel_launch(void* const* d_in, const int* in_sizes, int n_in,
                              void* d_out, int out_size, void* d_ws, size_t ws_size,
                              hipStream_t stream) {
    const float* x   = (const float*)d_in[0];
    const float* hw_ = (const float*)d_in[1];
    const float* l1w = (const float*)d_in[2];
    const float* l2w = (const float*)d_in[3];
    const int*   mi  = (const int*)d_in[4];
    const int*   ii  = (const int*)d_in[5];
    float*       out = (float*)d_out;

    // ws carve
    unsigned char*  flags = (unsigned char*)d_ws;
    size_t off = (NPIX + 15) & ~(size_t)15;
    unsigned short* Wp    = (unsigned short*)((char*)d_ws + off); off += 18 * 5 * 64 * 8 * 2;
    unsigned short* Ap2   = (unsigned short*)((char*)d_ws + off);

    const int half = NPIX / 2;
    k_flags<<<(half + 255) / 256, 256, 0, stream>>>(mi, ii, flags, half);
    k_wpack<<<(18 * 5 * 64 + 255) / 256, 256, 0, stream>>>(hw_, l1w, l2w, Wp, Ap2);
    k_main<<<dim3(WW / TC, HH / TR, BB), 256, 0, stream>>>(x, Wp, Ap2, flags, out);
}